// Round 1
// baseline (702.006 us; speedup 1.0000x reference)
//
#include <hip/hip_runtime.h>
#include <math.h>

#define E_TOTAL 8
#define NUM_LOCAL 4
#define HIDDEN 1024
#define FFN 4096
#define CAP 2048

typedef unsigned short ushort_t;
typedef __attribute__((ext_vector_type(8))) short short8;   // 8 bf16 (4 VGPRs)
typedef __attribute__((ext_vector_type(4))) float f32x4;    // MFMA accumulator

__device__ __forceinline__ unsigned short f2bf(float f) {
  unsigned int u = __float_as_uint(f);
  u += 0x7FFFu + ((u >> 16) & 1u);   // round-to-nearest-even
  return (unsigned short)(u >> 16);
}

__device__ __forceinline__ void gload_lds16(const void* g, void* l) {
  __builtin_amdgcn_global_load_lds(
      (const __attribute__((address_space(1))) void*)g,
      (__attribute__((address_space(3))) void*)l,
      16, 0, 0);
}

// fp32 -> bf16 bulk convert, float4 in / ushort4 out (16B read, 8B write per lane)
__global__ __launch_bounds__(256) void cvt_kernel(const float4* __restrict__ s,
                                                  ushort4* __restrict__ d) {
  const size_t i = (size_t)blockIdx.x * 256 + threadIdx.x;
  float4 v = s[i];
  d[i] = make_ushort4(f2bf(v.x), f2bf(v.y), f2bf(v.z), f2bf(v.w));
}

// NT GEMM: A [E][M][K] bf16 row-major, B [E][N][K] bf16 row-major (i.e. B^T),
// C[e][m][n] = sum_k A*B.  GELU_OUT: exact-erf GELU + bf16 store (to h).
// else: fp32 store * unpopular-expert mask (final output).
// m97 structure: 128x128 tile, BK=32, 4 waves each computing a 64x64 quadrant
// as 4x4 grid of 16x16x32 bf16 MFMA tiles. LDS 16KB, global_load_lds width 16.
template <int M, int N, int K, bool GELU_OUT>
__global__ __launch_bounds__(256, 2) void gemm_nt(
    const ushort_t* __restrict__ A, const ushort_t* __restrict__ B,
    void* __restrict__ Cout, const float* __restrict__ ot, int d0) {
  __shared__ ushort_t lds_a[128 * 32];  // 8 KB, row-major [128][32], no pad
  __shared__ ushort_t lds_b[128 * 32];  // (global_load_lds needs lane-contiguous)

  const int e = blockIdx.z;
  const int bm = blockIdx.x * 128;
  const int bn = blockIdx.y * 128;
  const int t = threadIdx.x;
  const int wave = t >> 6, lane = t & 63;
  const int wr = wave >> 1, wc = wave & 1;     // wave quadrant in 128x128
  const int quad = lane >> 4, l16 = lane & 15;
  const int sub = lane >> 2, qc = lane & 3;    // staging: 4 lanes per row

  const ushort_t* Ag = A + (size_t)e * M * K + (size_t)bm * K;
  const ushort_t* Bg = B + (size_t)e * N * K + (size_t)bn * K;

  f32x4 acc[4][4];
#pragma unroll
  for (int i = 0; i < 4; ++i)
#pragma unroll
    for (int j = 0; j < 4; ++j) {
      f32x4 z = {0.f, 0.f, 0.f, 0.f};
      acc[i][j] = z;
    }

  for (int kb = 0; kb < K / 32; ++kb) {
    // ---- stage 128x32 A tile and B tile to LDS ----
    // Each global_load_lds: 64 lanes x 16B = 16 rows of 64B. 8 chunks per
    // tile; wave w stages chunks {w, w+4}. LDS dest = base + lane*16B,
    // matching row-major [128][32] exactly (chunk*1024B + lane*16B).
    const ushort_t* Ak = Ag + kb * 32 + (size_t)sub * K + qc * 8;
    const ushort_t* Bk = Bg + kb * 32 + (size_t)sub * K + qc * 8;
#pragma unroll
    for (int r = 0; r < 2; ++r) {
      const int chunk = r * 4 + wave;
      gload_lds16(Ak + (size_t)chunk * 16 * K, &lds_a[chunk * 512]);
      gload_lds16(Bk + (size_t)chunk * 16 * K, &lds_b[chunk * 512]);
    }
    __syncthreads();  // compiler emits s_waitcnt vmcnt(0) before s_barrier

    // ---- LDS -> fragments (ds_read_b128) ----
    // A operand: lane holds A[m=l16][k=quad*8+j]; B operand: B[k][n=l16].
    short8 af[4], bf[4];
#pragma unroll
    for (int i = 0; i < 4; ++i) {
      af[i] = *(const short8*)&lds_a[(wr * 64 + i * 16 + l16) * 32 + quad * 8];
      bf[i] = *(const short8*)&lds_b[(wc * 64 + i * 16 + l16) * 32 + quad * 8];
    }
#pragma unroll
    for (int mi = 0; mi < 4; ++mi)
#pragma unroll
      for (int ni = 0; ni < 4; ++ni)
        acc[mi][ni] = __builtin_amdgcn_mfma_f32_16x16x32_bf16(
            af[mi], bf[ni], acc[mi][ni], 0, 0, 0);
    __syncthreads();
  }

  // ---- epilogue: C/D layout col=lane&15, row=quad*4+reg (m89-verified) ----
  if (GELU_OUT) {
    ushort_t* C = (ushort_t*)Cout + (size_t)e * M * N +
                  (size_t)(bm + wr * 64) * N + (bn + wc * 64);
#pragma unroll
    for (int mi = 0; mi < 4; ++mi)
#pragma unroll
      for (int r = 0; r < 4; ++r) {
        const int row = mi * 16 + quad * 4 + r;
#pragma unroll
        for (int ni = 0; ni < 4; ++ni) {
          float v = acc[mi][ni][r];
          v = 0.5f * v * (1.f + erff(v * 0.70710678118654752f));  // exact GELU
          C[(size_t)row * N + ni * 16 + l16] = f2bf(v);
        }
      }
  } else {
    // unpopular experts (e >= NUM_LOCAL) masked by gating activity;
    // locals always kept. Computed every call -> uniform work, graph-safe.
    float mask = 1.f;
    if (e >= NUM_LOCAL) {
      float s = 0.f;
      for (int b = 0; b < d0; ++b) s += ot[b * E_TOTAL + e];
      mask = (s != 0.f) ? 1.f : 0.f;
    }
    float* C = (float*)Cout + (size_t)e * M * N +
               (size_t)(bm + wr * 64) * N + (bn + wc * 64);
#pragma unroll
    for (int mi = 0; mi < 4; ++mi)
#pragma unroll
      for (int r = 0; r < 4; ++r) {
        const int row = mi * 16 + quad * 4 + r;
#pragma unroll
        for (int ni = 0; ni < 4; ++ni)
          C[(size_t)row * N + ni * 16 + l16] = acc[mi][ni][r] * mask;
      }
  }
}

extern "C" void kernel_launch(void* const* d_in, const int* in_sizes, int n_in,
                              void* d_out, int out_size, void* d_ws,
                              size_t ws_size, hipStream_t stream) {
  const float* ot = (const float*)d_in[0];   // [D0][E] gating activity
  const float* x  = (const float*)d_in[1];   // [D0][E][CAP][HIDDEN] fp32
  const float* w0 = (const float*)d_in[2];   // [E][FFN][HIDDEN] fp32
  const float* w3 = (const float*)d_in[3];   // [E][HIDDEN][FFN] fp32
  const int d0 = in_sizes[0] / E_TOTAL;

  // Workspace layout (224 MB total):
  //   [0,32MB)    x_bf16      -- later overwritten by w3_bf16
  //   [32,96MB)   w0_bf16     -- (w3_bf16 occupies [0,64MB) after GEMM1)
  //   [96,224MB)  h bf16 [E][CAP][FFN]
  char* ws = (char*)d_ws;
  ushort_t* xb  = (ushort_t*)ws;
  ushort_t* w0b = (ushort_t*)(ws + (size_t)32 * 1024 * 1024);
  ushort_t* w3b = (ushort_t*)ws;  // reuses x/w0 region AFTER gemm1 (stream order)
  ushort_t* h   = (ushort_t*)(ws + (size_t)96 * 1024 * 1024);

  const int n4x = E_TOTAL * CAP * HIDDEN / 4;  // 4,194,304 float4
  const int n4w = E_TOTAL * FFN * HIDDEN / 4;  // 8,388,608 float4

  cvt_kernel<<<n4x / 256, 256, 0, stream>>>((const float4*)x, (ushort4*)xb);
  cvt_kernel<<<n4w / 256, 256, 0, stream>>>((const float4*)w0, (ushort4*)w0b);

  // GEMM1: h[e] = GELU(x[e] (2048x1024) * w0[e]^T (1024x4096)) -> bf16
  gemm_nt<CAP, FFN, HIDDEN, true>
      <<<dim3(CAP / 128, FFN / 128, E_TOTAL), 256, 0, stream>>>(
          xb, w0b, h, nullptr, d0);

  // convert w3 only now (stream-ordered after gemm1; reuses x/w0 scratch)
  cvt_kernel<<<n4w / 256, 256, 0, stream>>>((const float4*)w3, (ushort4*)w3b);

  // GEMM2: out[e] = h[e] (2048x4096) * w3[e]^T (4096x1024), masked, fp32
  gemm_nt<CAP, HIDDEN, FFN, false>
      <<<dim3(CAP / 128, HIDDEN / 128, E_TOTAL), 256, 0, stream>>>(
          h, w3b, d_out, ot, d0);
}

// Round 2
// 677.020 us; speedup vs baseline: 1.0369x; 1.0369x over previous
//
#include <hip/hip_runtime.h>
#include <math.h>

#define E_TOTAL 8
#define NUM_LOCAL 4
#define HIDDEN 1024
#define FFN 4096
#define CAP 2048

typedef unsigned short ushort_t;
typedef __attribute__((ext_vector_type(8))) short short8;     // 8 bf16 (4 VGPRs)
typedef __attribute__((ext_vector_type(8))) unsigned short u16x8;
typedef __attribute__((ext_vector_type(4))) float f32x4;      // MFMA accumulator

__device__ __forceinline__ unsigned short f2bf(float f) {
  unsigned int u = __float_as_uint(f);
  u += 0x7FFFu + ((u >> 16) & 1u);   // round-to-nearest-even
  return (unsigned short)(u >> 16);
}

__device__ __forceinline__ void gload_lds16(const void* g, void* l) {
  __builtin_amdgcn_global_load_lds(
      (const __attribute__((address_space(1))) void*)g,
      (__attribute__((address_space(3))) void*)l,
      16, 0, 0);
}

// fp32 -> bf16 bulk convert: 8 elements/lane (2x float4 in, 1x 16B store out)
__global__ __launch_bounds__(256) void cvt_kernel(const float4* __restrict__ s,
                                                  u16x8* __restrict__ d) {
  const size_t i = (size_t)blockIdx.x * 256 + threadIdx.x;
  float4 a = s[2 * i], b = s[2 * i + 1];
  u16x8 o;
  o[0] = f2bf(a.x); o[1] = f2bf(a.y); o[2] = f2bf(a.z); o[3] = f2bf(a.w);
  o[4] = f2bf(b.x); o[5] = f2bf(b.y); o[6] = f2bf(b.z); o[7] = f2bf(b.w);
  d[i] = o;
}

// NT GEMM: A [E][M][K] bf16 row-major, B [E][N][K] bf16 row-major (B^T),
// C[e][m][n] = sum_k A*B.  BK=64: 32 MFMA per barrier-pair (halves the
// vmcnt(0)+s_barrier drain frequency vs BK=32).  LDS rows are 128B so all
// rows alias bank 0 -> rotate swizzle: LDS slot s (16B) of row r holds
// global k-chunk (s + (r&7)) & 7.  Reads of chunk c use slot (c - r) & 7:
// each 16-lane ds_read_b128 phase then covers all 8 bank-groups twice
// (2-way = free, m136), instead of 8/16-way serialization.
template <int M, int N, int K, bool GELU_OUT>
__global__ __launch_bounds__(256, 2) void gemm_nt(
    const ushort_t* __restrict__ A, const ushort_t* __restrict__ B,
    void* __restrict__ Cout, const float* __restrict__ ot, int d0) {
  __shared__ ushort_t lds_a[128 * 64];  // 16 KB, row-major [128][64], swizzled
  __shared__ ushort_t lds_b[128 * 64];  // 32 KB total -> LDS allows 5 blk/CU

  const int e = blockIdx.z;
  const int bm = blockIdx.x * 128;
  const int bn = blockIdx.y * 128;
  const int t = threadIdx.x;
  const int wave = t >> 6, lane = t & 63;
  const int wr = wave >> 1, wc = wave & 1;     // wave quadrant in 128x128
  const int quad = lane >> 4, l16 = lane & 15;
  const int r8 = lane >> 3;                    // staging: row within 8-row group
  const int s8 = lane & 7;                     // staging: LDS slot within row
  const int g8 = (s8 + r8) & 7;                // staging: swizzled global chunk

  // per-lane global offset inside a tile: row r8 (mod 8), k-chunk g8 (16B)
  const ushort_t* Ag = A + (size_t)e * M * K + (size_t)(bm + r8) * K + g8 * 8;
  const ushort_t* Bg = B + (size_t)e * N * K + (size_t)(bn + r8) * K + g8 * 8;

  f32x4 acc[4][4];
#pragma unroll
  for (int i = 0; i < 4; ++i)
#pragma unroll
    for (int j = 0; j < 4; ++j) {
      f32x4 z = {0.f, 0.f, 0.f, 0.f};
      acc[i][j] = z;
    }

  for (int kb = 0; kb < K / 64; ++kb) {
    // ---- stage 128x64 A and B tiles ----
    // One global_load_lds(16B) covers 8 rows x 128B = 1KB, lane-contiguous.
    // 16 instrs per matrix per block; wave w takes row-groups (j*4+w)*8.
    const size_t ko = (size_t)kb * 64;
#pragma unroll
    for (int j = 0; j < 4; ++j) {
      const int R = (j * 4 + wave) * 8;
      gload_lds16(Ag + ko + (size_t)R * K, &lds_a[R * 64]);
      gload_lds16(Bg + ko + (size_t)R * K, &lds_b[R * 64]);
    }
    __syncthreads();

#pragma unroll
    for (int ks = 0; ks < 2; ++ks) {
      // fragment k-chunks c = ks*4 + quad (8 bf16 = 16B... chunk is 8 elems
      // = 16B = one slot); read chunk c of row r at slot (c - r) & 7
      short8 af[4], bfr[4];
      const int c = ks * 4 + quad;
#pragma unroll
      for (int i = 0; i < 4; ++i) {
        const int ra = wr * 64 + i * 16 + l16;
        const int rb = wc * 64 + i * 16 + l16;
        af[i]  = *(const short8*)&lds_a[ra * 64 + ((c - ra) & 7) * 8];
        bfr[i] = *(const short8*)&lds_b[rb * 64 + ((c - rb) & 7) * 8];
      }
#pragma unroll
      for (int mi = 0; mi < 4; ++mi)
#pragma unroll
        for (int ni = 0; ni < 4; ++ni)
          acc[mi][ni] = __builtin_amdgcn_mfma_f32_16x16x32_bf16(
              af[mi], bfr[ni], acc[mi][ni], 0, 0, 0);
    }
    __syncthreads();
  }

  // ---- epilogue: C/D layout col=lane&15, row=quad*4+reg (m89-verified) ----
  if (GELU_OUT) {
    ushort_t* C = (ushort_t*)Cout + (size_t)e * M * N +
                  (size_t)(bm + wr * 64) * N + (bn + wc * 64);
#pragma unroll
    for (int mi = 0; mi < 4; ++mi)
#pragma unroll
      for (int r = 0; r < 4; ++r) {
        const int row = mi * 16 + quad * 4 + r;
#pragma unroll
        for (int ni = 0; ni < 4; ++ni) {
          float v = acc[mi][ni][r];
          v = 0.5f * v * (1.f + erff(v * 0.70710678118654752f));  // exact GELU
          C[(size_t)row * N + ni * 16 + l16] = f2bf(v);
        }
      }
  } else {
    float mask = 1.f;
    if (e >= NUM_LOCAL) {
      float s = 0.f;
      for (int b = 0; b < d0; ++b) s += ot[b * E_TOTAL + e];
      mask = (s != 0.f) ? 1.f : 0.f;
    }
    float* C = (float*)Cout + (size_t)e * M * N +
               (size_t)(bm + wr * 64) * N + (bn + wc * 64);
#pragma unroll
    for (int mi = 0; mi < 4; ++mi)
#pragma unroll
      for (int r = 0; r < 4; ++r) {
        const int row = mi * 16 + quad * 4 + r;
#pragma unroll
        for (int ni = 0; ni < 4; ++ni)
          C[(size_t)row * N + ni * 16 + l16] = acc[mi][ni][r] * mask;
      }
  }
}

extern "C" void kernel_launch(void* const* d_in, const int* in_sizes, int n_in,
                              void* d_out, int out_size, void* d_ws,
                              size_t ws_size, hipStream_t stream) {
  const float* ot = (const float*)d_in[0];   // [D0][E] gating activity
  const float* x  = (const float*)d_in[1];   // [D0][E][CAP][HIDDEN] fp32
  const float* w0 = (const float*)d_in[2];   // [E][FFN][HIDDEN] fp32
  const float* w3 = (const float*)d_in[3];   // [E][HIDDEN][FFN] fp32
  const int d0 = in_sizes[0] / E_TOTAL;

  // Workspace layout (224 MB):
  //   [0,32MB)    x_bf16   -- later overwritten by w3_bf16
  //   [32,96MB)   w0_bf16
  //   [96,224MB)  h bf16 [E][CAP][FFN]
  char* ws = (char*)d_ws;
  ushort_t* xb  = (ushort_t*)ws;
  ushort_t* w0b = (ushort_t*)(ws + (size_t)32 * 1024 * 1024);
  ushort_t* w3b = (ushort_t*)ws;  // reuses x/w0 region AFTER gemm1 (stream order)
  ushort_t* h   = (ushort_t*)(ws + (size_t)96 * 1024 * 1024);

  const int nx = E_TOTAL * CAP * HIDDEN;  // 16.8M elements
  const int nw = E_TOTAL * FFN * HIDDEN;  // 33.6M elements

  cvt_kernel<<<nx / (256 * 8), 256, 0, stream>>>((const float4*)x, (u16x8*)xb);
  cvt_kernel<<<nw / (256 * 8), 256, 0, stream>>>((const float4*)w0, (u16x8*)w0b);

  // GEMM1: h[e] = GELU(x[e] (2048x1024) * w0[e]^T (1024x4096)) -> bf16
  gemm_nt<CAP, FFN, HIDDEN, true>
      <<<dim3(CAP / 128, FFN / 128, E_TOTAL), 256, 0, stream>>>(
          xb, w0b, h, nullptr, d0);

  cvt_kernel<<<nw / (256 * 8), 256, 0, stream>>>((const float4*)w3, (u16x8*)w3b);

  // GEMM2: out[e] = h[e] (2048x4096) * w3[e]^T (4096x1024), masked, fp32
  gemm_nt<CAP, HIDDEN, FFN, false>
      <<<dim3(CAP / 128, HIDDEN / 128, E_TOTAL), 256, 0, stream>>>(
          h, w3b, d_out, ot, d0);
}